// Round 3
// baseline (165.176 us; speedup 1.0000x reference)
//
#include <hip/hip_runtime.h>
#include <math.h>

// Problem constants (reference: B=4, N=2048, TIMESTEPS=1000, speed=0.01)
#define TIMESTEPS 1000
constexpr int Bc  = 4;
constexpr int Nc  = 2048;
constexpr int EcI = Nc * (Nc - 1) / 2;   // 2,096,128 edges per batch
constexpr int THREADS = 256;
constexpr int NB  = 2048;                // 4 batches x 512 block-slices (2 row-pairs each)

typedef int   i4v __attribute__((ext_vector_type(4)));
typedef float f4v __attribute__((ext_vector_type(4)));

__device__ __forceinline__ int imin(int a, int b) { return a < b ? a : b; }

// Row-pair decomposition (unchanged from round 2, verified absmax=0):
//   pair p covers row a=p+1 (len la=p+1) and row rb=2047-p (len lb=rb; 0 for p=1023).
//   groups 0..Ga-1 are row a (j = 4*gg), groups Ga.. are row rb (j = 4*(gg-Ga)).
//   adj/u: j%4==0 -> genuinely 16B-aligned global_load_dwordx4.
//   q: packed index tri(row)+j, only 4B-aligned -> 4 scalar dwords (same 16 lines,
//   L1-resident across the 4).
//
// Round-3 change: PURE LOAD PHASE then PURE COMPUTE PHASE. All 24 VMEM
// instructions of a thread's work are issued before any consumption, so the
// wave keeps ~24 requests in flight instead of ~6 (the round-2 codegen, VGPR=28,
// waited vmcnt(0) per group). launch_bounds(256,4) caps VGPR at 128 so the
// register allocator cannot re-serialize the batch.

__device__ __forceinline__ float edge_terms(
    const i4v& av, const f4v& uv, const f4v& qv, int jg, int len,
    float p0, float p1, float qt00, float qt01, float qt10, float qt11)
{
    float s = 0.0f;
    #pragma unroll
    for (int k = 0; k < 4; ++k) {
        const int   a0 = av[k];
        const float ps = a0 ? p1 : p0;
        const bool  x  = uv[k] < ps;
        const float t0 = x ? qt01 : qt00;
        const float t1 = x ? qt11 : qt10;
        const float qt = a0 ? t1 : t0;
        const float qq = qv[k];
        const float term = fmaxf(qq, 0.0f) - qq * qt
                         + __logf(1.0f + __expf(-fabsf(qq)));
        s += (jg + k < len) ? term : 0.0f;   // branch-free row-end mask
    }
    return s;
}

__global__ __launch_bounds__(256, 4) void diff_loss_kernel(
    const int* __restrict__ adj, const int* __restrict__ t,
    const float* __restrict__ u, const float* __restrict__ q,
    double* __restrict__ partials)
{
    const int blk = blockIdx.x;
    const int b   = blk >> 9;                 // batch
    const int ip  = blk & 511;                // handles pairs 2*ip, 2*ip+1
    const int tb  = t[b];

    // Qt[k] built with ts=k+1: flip = 0.5*(1 - 0.98^(k+1))
    const float f_t   = 0.5f * (1.0f - powf(0.98f, (float)(tb + 1)));
    const int   tpe   = (tb == 0) ? TIMESTEPS : tb;   // Qt[t-1], wrap -1 -> 999
    const float f_p   = 0.5f * (1.0f - powf(0.98f, (float)tpe));
    const float f0    = 0.01f;                        // Qt[0] flip = 0.5*(1-0.98)
    const float omf_t = 1.0f - f_t;

    const float p0   = f_t;                            // probs1 when a0==0
    const float p1   = omf_t;                          // probs1 when a0==1
    const float qt00 = f0          * f_p          / omf_t;  // a0=0,x=0
    const float qt01 = (1.0f - f0) * f_p          / f_t;    // a0=0,x=1
    const float qt10 = f0          * (1.0f - f_p) / f_t;    // a0=1,x=0
    const float qt11 = (1.0f - f0) * (1.0f - f_p) / omf_t;  // a0=1,x=1

    const int*   adjb = adj + ((size_t)b << 22);
    const float* ub   = u   + ((size_t)b << 22);
    const float* qb   = q   + (size_t)b * EcI;

    const int tid = threadIdx.x;

    // ---------------- PHASE 1: issue ALL loads (24 VMEM / thread) -------------
    i4v av[4]; f4v uvv[4]; f4v qvv[4];
    int jgA[4], lenA[4];

    #pragma unroll
    for (int gi = 0; gi < 4; ++gi) {
        const int p   = 2 * ip + (gi >> 1);
        const int la  = p + 1;                    // row a index and length
        const int rbv = 2047 - p;                 // row b index
        const int lbv = (p == 1023) ? 0 : rbv;    // row b length (dup row masked)
        const int Ga  = (la + 3) >> 2;            // aligned groups in row a
        const int gg  = tid + ((gi & 1) << 8);    // group 0: tid, group 1: tid+256
        const bool ina = gg < Ga;
        const int row = ina ? la : rbv;
        lenA[gi] = ina ? la : lbv;
        const int jg  = (ina ? gg : (gg - Ga)) << 2;
        jgA[gi] = jg;
        const int base = (row << 11) + jg;        // 16B-aligned element offset
        av[gi]  = *(const i4v*)(adjb + base);     // global_load_dwordx4
        uvv[gi] = *(const f4v*)(ub   + base);     // global_load_dwordx4
        const int e = ((row * (row - 1)) >> 1) + jg;
        f4v qq;
        qq[0] = qb[imin(e,     EcI - 1)];
        qq[1] = qb[imin(e + 1, EcI - 1)];
        qq[2] = qb[imin(e + 2, EcI - 1)];
        qq[3] = qb[imin(e + 3, EcI - 1)];
        qvv[gi] = qq;
    }

    double acc = 0.0;

    // Tail: the 513th group per pair (exists iff row-a length % 4 != 0).
    // Loads sit under the guard but are issued here, joining the in-flight batch;
    // its compute waits for the whole batch anyway (lane-0 wave only).
    if (tid == 0) {
        #pragma unroll
        for (int pp = 0; pp < 2; ++pp) {
            const int p  = 2 * ip + pp;
            const int la = p + 1;
            if (la & 3) {
                const int rbv = 2047 - p;         // gg=512 >= Ga always -> row b
                const int lbv = (p == 1023) ? 0 : rbv;
                const int Ga  = (la + 3) >> 2;
                const int jg  = (512 - Ga) << 2;
                const int base = (rbv << 11) + jg;
                const i4v a2 = *(const i4v*)(adjb + base);
                const f4v u2 = *(const f4v*)(ub   + base);
                const int e = ((rbv * (rbv - 1)) >> 1) + jg;
                f4v q2;
                q2[0] = qb[imin(e,     EcI - 1)];
                q2[1] = qb[imin(e + 1, EcI - 1)];
                q2[2] = qb[imin(e + 2, EcI - 1)];
                q2[3] = qb[imin(e + 3, EcI - 1)];
                acc += (double)edge_terms(a2, u2, q2, jg, lbv,
                                          p0, p1, qt00, qt01, qt10, qt11);
            }
        }
    }

    // ---------------- PHASE 2: compute ----------------------------------------
    #pragma unroll
    for (int gi = 0; gi < 4; ++gi)
        acc += (double)edge_terms(av[gi], uvv[gi], qvv[gi], jgA[gi], lenA[gi],
                                  p0, p1, qt00, qt01, qt10, qt11);

    // wave (64) shuffle reduce, then cross-wave via LDS
    for (int off = 32; off > 0; off >>= 1)
        acc += __shfl_down(acc, off, 64);
    __shared__ double wsum[4];
    const int lane = threadIdx.x & 63, wid = threadIdx.x >> 6;
    if (lane == 0) wsum[wid] = acc;
    __syncthreads();
    if (threadIdx.x == 0)
        partials[blockIdx.x] = wsum[0] + wsum[1] + wsum[2] + wsum[3];
}

// Reduce per-block partials, write mean as f32.
__global__ __launch_bounds__(256) void final_reduce_kernel(
    const double* __restrict__ partials, int nb, float* __restrict__ out)
{
    double acc = 0.0;
    for (int idx = threadIdx.x; idx < nb; idx += blockDim.x)
        acc += partials[idx];
    for (int off = 32; off > 0; off >>= 1)
        acc += __shfl_down(acc, off, 64);
    __shared__ double wsum[4];
    const int lane = threadIdx.x & 63, wid = threadIdx.x >> 6;
    if (lane == 0) wsum[wid] = acc;
    __syncthreads();
    if (threadIdx.x == 0)
        out[0] = (float)((wsum[0] + wsum[1] + wsum[2] + wsum[3]) /
                         ((double)Bc * (double)EcI));
}

extern "C" void kernel_launch(void* const* d_in, const int* in_sizes, int n_in,
                              void* d_out, int out_size, void* d_ws, size_t ws_size,
                              hipStream_t stream) {
    const int*   adj = (const int*)d_in[0];   // adj_start (B,N,N) int32
    const int*   t   = (const int*)d_in[1];   // t (B,) int32
    const float* u   = (const float*)d_in[2]; // u (B,N,N) f32
    const float* q   = (const float*)d_in[3]; // q_approx (B,E) f32
    float*  out      = (float*)d_out;
    double* partials = (double*)d_ws;         // NB doubles (16 KB)

    diff_loss_kernel<<<NB, THREADS, 0, stream>>>(adj, t, u, q, partials);
    final_reduce_kernel<<<1, 256, 0, stream>>>(partials, NB, out);
}

// Round 4
// 164.780 us; speedup vs baseline: 1.0024x; 1.0024x over previous
//
#include <hip/hip_runtime.h>
#include <math.h>

// Problem constants (reference: B=4, N=2048, TIMESTEPS=1000, speed=0.01)
#define TIMESTEPS 1000
constexpr int Bc  = 4;
constexpr int Nc  = 2048;
constexpr int EcI = Nc * (Nc - 1) / 2;    // 2,096,128 edges per batch
constexpr int EG  = EcI / 4;              // 524,032 groups of 4 per batch

constexpr int BLKX    = 128;              // blocks per batch; grid = (128, 4)
constexpr int THREADS = 256;
constexpr int ITERS   = 8;                // 8 * 65,536 = 524,288 >= EG
constexpr int ITERSTRIDE = BLKX * THREADS * 2;   // 65,536 groups/iter/batch
// per thread, iteration k covers groups  g(k,0) = k*ITERSTRIDE + bx*512 + tid
// and                                    g(k,1) = g(k,0) + 256.
// Max g(k,0) = 7*65536 + 127*512 + 255 = 524,031 = EG-1  -> sub0 always valid.
// Only (k=7, bx=127, sub1) overflows: clamp the load, mask the contribution.

typedef int   i4v __attribute__((ext_vector_type(4)));
typedef float f4v __attribute__((ext_vector_type(4)));

__device__ __forceinline__ int imin(int a, int b) { return a < b ? a : b; }

struct GData { i4v av; f4v uv; f4v qv; };   // 12 VGPRs per in-flight group

// Issue one group's 9 VMEM loads (4 adj dwords, 4 u dwords, 1 q dwordx4).
// Same memory pattern as the round-0 kernel (verified absmax=0): sqrt
// triangular inversion + branchless row advance.
__device__ __forceinline__ GData issue_group(
    const int* __restrict__ adjb, const float* __restrict__ ub,
    const float* __restrict__ qb, int gc)
{
    GData d;
    const int e0 = gc << 2;                        // 8*e0+1 < 2^24: sqrt exact
    const float sf = sqrtf((float)(8 * e0 + 1));
    int i = (int)((1.0f + sf) * 0.5f);
    if (i * (i - 1) / 2 > e0)  --i;                // fixup rounding
    if (i * (i + 1) / 2 <= e0) ++i;
    int jj = e0 - i * (i - 1) / 2;                 // 0 <= jj < i
    d.qv = *(const f4v*)(qb + e0);                 // 16B-aligned dwordx4
    int ii = i;
    #pragma unroll
    for (int k = 0; k < 4; ++k) {
        const bool adv = (jj >= ii);               // at most one row step per k
        ii += adv;
        jj = adv ? 0 : jj;
        const int base = (ii << 11) + jj;
        d.av[k] = adjb[base];
        d.uv[k] = ub[base];
        ++jj;
    }
    return d;
}

__device__ __forceinline__ float group_sum(const GData& d,
    float p0, float p1, float qt00, float qt01, float qt10, float qt11)
{
    float s = 0.0f;
    #pragma unroll
    for (int k = 0; k < 4; ++k) {
        const int   a0 = d.av[k];
        const float ps = a0 ? p1 : p0;
        const bool  x  = d.uv[k] < ps;
        const float t0 = x ? qt01 : qt00;
        const float t1 = x ? qt11 : qt10;
        const float qt = a0 ? t1 : t0;
        const float qq = d.qv[k];
        s += fmaxf(qq, 0.0f) - qq * qt + __logf(1.0f + __expf(-fabsf(qq)));
    }
    return s;
}

// Software-pipelined (depth 2) persistent kernel: loads for iteration k+2 are
// issued while computing iteration k. Loop-carried prefetch cannot be sunk
// across the backedge by the scheduler -> the batch survives codegen (unlike
// rounds 1-3's straight-line bodies). launch_bounds(256,2) gives regalloc a
// 256-VGPR budget so pressure never forces re-serialization.
__global__ __launch_bounds__(256, 2) void diff_loss_kernel(
    const int* __restrict__ adj, const int* __restrict__ t,
    const float* __restrict__ u, const float* __restrict__ q,
    double* __restrict__ partials)
{
    const int b  = blockIdx.y;                 // batch (wave-uniform)
    const int bx = blockIdx.x;                 // 0..127
    const int tb = t[b];

    // Qt[k] built with ts=k+1: flip = 0.5*(1 - 0.98^(k+1))
    const float f_t   = 0.5f * (1.0f - powf(0.98f, (float)(tb + 1)));
    const int   tpe   = (tb == 0) ? TIMESTEPS : tb;   // Qt[t-1], wrap -1 -> 999
    const float f_p   = 0.5f * (1.0f - powf(0.98f, (float)tpe));
    const float f0    = 0.01f;                        // Qt[0] flip
    const float omf_t = 1.0f - f_t;

    const float p0   = f_t;                            // probs1 when a0==0
    const float p1   = omf_t;                          // probs1 when a0==1
    const float qt00 = f0          * f_p          / omf_t;  // a0=0,x=0
    const float qt01 = (1.0f - f0) * f_p          / f_t;    // a0=0,x=1
    const float qt10 = f0          * (1.0f - f_p) / f_t;    // a0=1,x=0
    const float qt11 = (1.0f - f0) * (1.0f - f_p) / omf_t;  // a0=1,x=1

    const int*   adjb = adj + ((size_t)b << 22);
    const float* ub   = u   + ((size_t)b << 22);
    const float* qb   = q   + (size_t)b * EcI;

    const int gbase = bx * 512 + threadIdx.x;

    // ---- prologue: 2 iterations of loads in flight ----
    GData A0 = issue_group(adjb, ub, qb, gbase);
    GData B0 = issue_group(adjb, ub, qb, gbase + 256);
    GData A1 = issue_group(adjb, ub, qb, gbase + ITERSTRIDE);
    GData B1 = issue_group(adjb, ub, qb, gbase + ITERSTRIDE + 256);

    double acc = 0.0;

    #pragma unroll 1   // keep the backedge: full unroll would re-enable sinking
    for (int k = 0; k < ITERS; ++k) {
        GData An = A1, Bn = B1;                // defined when guard is false
        if (k + 2 < ITERS) {                   // wave-uniform branch
            const int gk = gbase + (k + 2) * ITERSTRIDE;
            An = issue_group(adjb, ub, qb, gk);                    // always valid
            Bn = issue_group(adjb, ub, qb, imin(gk + 256, EG - 1)); // clamp tail
        }

        const float sA = group_sum(A0, p0, p1, qt00, qt01, qt10, qt11);
        const float sB = group_sum(B0, p0, p1, qt00, qt01, qt10, qt11);
        const int g1 = gbase + k * ITERSTRIDE + 256;
        acc += (double)(sA + ((g1 < EG) ? sB : 0.0f));   // mask overflow groups

        A0 = A1; B0 = B1; A1 = An; B1 = Bn;    // rotate pipeline
    }

    // wave (64) shuffle reduce, then cross-wave via LDS
    for (int off = 32; off > 0; off >>= 1)
        acc += __shfl_down(acc, off, 64);
    __shared__ double wsum[4];
    const int lane = threadIdx.x & 63, wid = threadIdx.x >> 6;
    if (lane == 0) wsum[wid] = acc;
    __syncthreads();
    if (threadIdx.x == 0)
        partials[blockIdx.y * BLKX + blockIdx.x] =
            wsum[0] + wsum[1] + wsum[2] + wsum[3];
}

// Reduce per-block partials, write mean as f32.
__global__ __launch_bounds__(256) void final_reduce_kernel(
    const double* __restrict__ partials, int nb, float* __restrict__ out)
{
    double acc = 0.0;
    for (int idx = threadIdx.x; idx < nb; idx += blockDim.x)
        acc += partials[idx];
    for (int off = 32; off > 0; off >>= 1)
        acc += __shfl_down(acc, off, 64);
    __shared__ double wsum[4];
    const int lane = threadIdx.x & 63, wid = threadIdx.x >> 6;
    if (lane == 0) wsum[wid] = acc;
    __syncthreads();
    if (threadIdx.x == 0)
        out[0] = (float)((wsum[0] + wsum[1] + wsum[2] + wsum[3]) /
                         ((double)Bc * (double)EcI));
}

extern "C" void kernel_launch(void* const* d_in, const int* in_sizes, int n_in,
                              void* d_out, int out_size, void* d_ws, size_t ws_size,
                              hipStream_t stream) {
    const int*   adj = (const int*)d_in[0];   // adj_start (B,N,N) int32
    const int*   t   = (const int*)d_in[1];   // t (B,) int32
    const float* u   = (const float*)d_in[2]; // u (B,N,N) f32
    const float* q   = (const float*)d_in[3]; // q_approx (B,E) f32
    float*  out      = (float*)d_out;
    double* partials = (double*)d_ws;         // 512 doubles (4 KB)

    dim3 grid(BLKX, Bc);
    diff_loss_kernel<<<grid, THREADS, 0, stream>>>(adj, t, u, q, partials);
    final_reduce_kernel<<<1, 256, 0, stream>>>(partials, BLKX * Bc, out);
}